// Round 2
// baseline (284.290 us; speedup 1.0000x reference)
//
#include <hip/hip_runtime.h>
#include <stdint.h>

#define KNN 16

// Map float to a uint32 whose unsigned order matches the float order
// (handles tiny negative dists from fp rounding).
__device__ __forceinline__ uint32_t fkey(float f) {
    uint32_t u = __float_as_uint(f);
    return (u & 0x80000000u) ? ~u : (u | 0x80000000u);
}

// One wave per query. Each lane scans refs lane, lane+64, ... keeping a
// sorted (ascending) top-16 in registers, gated by a wave-global threshold
// tau = wave-min of lane d[15] (a sound upper bound on the final global 16th
// smallest distance: any candidate with dist > tau can never be selected).
// Then a 16-round wave-wide u64-min merge reproduces jax.lax.top_k ordering
// exactly (dist asc, idx asc on tie).
__global__ __launch_bounds__(256) void knn_kernel(
    const float* __restrict__ xyz_prev, const float* __restrict__ xyz_cur,
    int* __restrict__ knn_idx, int n_prev, int n_cur)
{
    // 17-u64 stride per lane: lane base = lane*136B -> bank (2*lane)%32,
    // 2-way aliasing only (free), vs 64-way at stride 16.
    __shared__ unsigned long long lds[4 * 64 * 17];
    const int wave = threadIdx.x >> 6;
    const int lane = threadIdx.x & 63;
    const int q = blockIdx.x * 4 + wave;
    if (q >= n_cur) return;  // wave-uniform exit, no __syncthreads in kernel

    const float qx = xyz_cur[3 * q + 0];
    const float qy = xyz_cur[3 * q + 1];
    const float qz = xyz_cur[3 * q + 2];
    // Mirror reference fp32 op order; q2 is a per-query constant (can't change argsort)
    const float q2 = __fadd_rn(__fadd_rn(__fmul_rn(qx, qx), __fmul_rn(qy, qy)),
                               __fmul_rn(qz, qz));

    float d[KNN];
    int   id[KNN];
#pragma unroll
    for (int j = 0; j < KNN; ++j) { d[j] = 3.4e38f; id[j] = 0x7fffffff; }

    float tau = 3.4e38f;  // wave-uniform upper bound on final 16th-best dist

    const int n_iter = (n_prev + 63) >> 6;  // wave-uniform trip count
    for (int t = 0; t < n_iter; ++t) {
        const int r = (t << 6) + lane;
        float dist = 3.4e38f;
        if (r < n_prev) {
            const float rx = xyz_prev[3 * r + 0];
            const float ry = xyz_prev[3 * r + 1];
            const float rz = xyz_prev[3 * r + 2];
            const float r2 = __fadd_rn(__fadd_rn(__fmul_rn(rx, rx), __fmul_rn(ry, ry)),
                                       __fmul_rn(rz, rz));
            // Eigen/XLA-style fma accumulation chain for the dot product
            const float cr = __fmaf_rn(rz, qz, __fmaf_rn(ry, qy, __fmul_rn(rx, qx)));
            dist = __fsub_rn(__fadd_rn(q2, r2), __fmul_rn(2.0f, cr));
        }

        // Insert iff it belongs in the lane-local top-16 (strict < keeps the
        // earlier/lower idx on exact ties) AND it could still matter globally
        // (<= tau: only dist > tau >= final-16th is discarded -> always safe).
        const bool hit = (dist <= tau) && (dist < d[KNN - 1]);
        if (__any(hit)) {
            if (hit) {
                d[KNN - 1] = dist;
                id[KNN - 1] = r;
#pragma unroll
                for (int j = KNN - 1; j >= 1; --j) {
                    const float dj = d[j], djm = d[j - 1];
                    const int   ij = id[j], ijm = id[j - 1];
                    const bool sw = dj < djm;
                    d[j - 1]  = sw ? dj : djm;
                    d[j]      = sw ? djm : dj;
                    id[j - 1] = sw ? ij : ijm;
                    id[j]     = sw ? ijm : ij;
                }
            }
        }
        // Refresh tau every 8 iterations at a wave-uniform point (all lanes
        // active for the shuffles). Staleness only admits extra inserts.
        if ((t & 7) == 7) {
            float w = d[KNN - 1];
#pragma unroll
            for (int s = 1; s < 64; s <<= 1)
                w = fminf(w, __shfl_xor(w, s, 64));
            tau = w;
        }
    }

    // Spill own sorted list to LDS so the head pointer can be a dynamic index.
    unsigned long long* my = &lds[(size_t)(wave * 64 + lane) * 17];
#pragma unroll
    for (int j = 0; j < KNN; ++j)
        my[j] = ((unsigned long long)fkey(d[j]) << 32) | (uint32_t)id[j];
    my[KNN] = ~0ull;  // sentinel (head==16 is provably never read, belt+braces)

    // 16 rounds: wave-wide min of the 64 list heads. Real keys are unique
    // (ref idx appears in exactly one lane), so exactly one lane advances.
    int head = 0;
    unsigned long long res = 0;
    for (int rr = 0; rr < KNN; ++rr) {
        const unsigned long long k = my[head];
        unsigned long long m = k;
#pragma unroll
        for (int s = 1; s < 64; s <<= 1) {
            const unsigned long long o = __shfl_xor(m, s, 64);
            m = (o < m) ? o : m;
        }
        if (k == m) ++head;
        if (lane == rr) res = m;
    }
    if (lane < KNN)
        knn_idx[q * KNN + lane] = (int)(res & 0xffffffffu);
}

// One wave per QUERY: load the shared cur row once, issue all 16 independent
// gathered prev-row float4 loads (16 KB in flight per wave), then stream the
// 32 stores. out[q*16+j] = [prev[idx[q][j]] - cur[q], cur[q]].
__global__ __launch_bounds__(256) void combine_kernel(
    const float* __restrict__ feat_prev, const float* __restrict__ feat_cur,
    const int* __restrict__ knn_idx, float* __restrict__ out,
    int n_cur, int c4)
{
    const int q = blockIdx.x * 4 + (threadIdx.x >> 6);
    const int lane = threadIdx.x & 63;
    if (q >= n_cur) return;

    int nb[KNN];
#pragma unroll
    for (int j = 0; j < KNN; ++j)
        nb[j] = knn_idx[q * KNN + j];

    const float4* pbase = (const float4*)feat_prev;
    const float4* crow  = (const float4*)feat_cur + (size_t)q * c4;
    const int c8 = 2 * c4;  // output row length in float4

    for (int i = lane; i < c4; i += 64) {
        const float4 c = crow[i];
        float4 p[KNN];
#pragma unroll
        for (int j = 0; j < KNN; ++j)
            p[j] = pbase[(size_t)nb[j] * c4 + i];

#pragma unroll
        for (int j = 0; j < KNN; ++j) {
            float4 dd;
            dd.x = p[j].x - c.x;
            dd.y = p[j].y - c.y;
            dd.z = p[j].z - c.z;
            dd.w = p[j].w - c.w;
            float4* orow = (float4*)out + (size_t)(q * KNN + j) * c8;
            orow[i]      = dd;
            orow[c4 + i] = c;
        }
    }
}

extern "C" void kernel_launch(void* const* d_in, const int* in_sizes, int n_in,
                              void* d_out, int out_size, void* d_ws, size_t ws_size,
                              hipStream_t stream) {
    const float* xyz_prev  = (const float*)d_in[0];
    const float* xyz_cur   = (const float*)d_in[1];
    const float* feat_prev = (const float*)d_in[2];
    const float* feat_cur  = (const float*)d_in[3];
    float* out = (float*)d_out;

    const int n_prev = in_sizes[0] / 3;
    const int n_cur  = in_sizes[1] / 3;
    const int C      = in_sizes[2] / n_prev;   // 256

    int* knn = (int*)d_ws;                     // n_cur*KNN*4 = 256 KB scratch

    const int knn_blocks = (n_cur + 3) / 4;    // 4 waves (queries) per block
    knn_kernel<<<knn_blocks, 256, 0, stream>>>(xyz_prev, xyz_cur, knn, n_prev, n_cur);

    const int cmb_blocks = (n_cur + 3) / 4;    // 4 waves (queries) per block
    combine_kernel<<<cmb_blocks, 256, 0, stream>>>(feat_prev, feat_cur, knn, out,
                                                   n_cur, C / 4);
}

// Round 3
// 230.604 us; speedup vs baseline: 1.2328x; 1.2328x over previous
//
#include <hip/hip_runtime.h>
#include <stdint.h>

#define KNN 16

typedef float vfloat4 __attribute__((ext_vector_type(4)));

// Map float to a uint32 whose unsigned order matches the float order
// (handles tiny negative dists from fp rounding).
__device__ __forceinline__ uint32_t fkey(float f) {
    uint32_t u = __float_as_uint(f);
    return (u & 0x80000000u) ? ~u : (u | 0x80000000u);
}

// One wave per query. The wave maintains ONE sorted top-16 distributed across
// lanes 0..15 (one u64 key per lane: fkey(dist)<<32 | idx, so u64 order ==
// (dist asc, idx asc) == jax.lax.top_k stable order). tau = lane-15 key is the
// EXACT running global 16th-best, so the ballot gate fires ~16*ln(Nr/16) ~= 100
// times total instead of every iteration. Warmup: bitonic-sort the first 64
// candidates across lanes, lanes 0..15 keep their element.
__global__ __launch_bounds__(256) void knn_kernel(
    const float* __restrict__ xyz_prev, const float* __restrict__ xyz_cur,
    int* __restrict__ knn_idx, int n_prev, int n_cur)
{
    const int lane = threadIdx.x & 63;
    const int q = blockIdx.x * 4 + (threadIdx.x >> 6);
    if (q >= n_cur) return;  // wave-uniform

    const float qx = xyz_cur[3 * q + 0];
    const float qy = xyz_cur[3 * q + 1];
    const float qz = xyz_cur[3 * q + 2];
    // Mirror reference fp32 op order (bit-exact vs np ref — verified absmax 0).
    // q2 is a per-query constant (cannot change the argsort).
    const float q2 = __fadd_rn(__fadd_rn(__fmul_rn(qx, qx), __fmul_rn(qy, qy)),
                               __fmul_rn(qz, qz));

    // ---- candidate key for iteration t (this lane's ref r = t*64+lane) ----
    auto distkey = [&](int t) -> unsigned long long {
        const int r = (t << 6) + lane;
        if (r >= n_prev) return ~0ull;  // never beats any real key
        const float rx = xyz_prev[3 * r + 0];
        const float ry = xyz_prev[3 * r + 1];
        const float rz = xyz_prev[3 * r + 2];
        const float r2 = __fadd_rn(__fadd_rn(__fmul_rn(rx, rx), __fmul_rn(ry, ry)),
                                   __fmul_rn(rz, rz));
        const float cr = __fmaf_rn(rz, qz, __fmaf_rn(ry, qy, __fmul_rn(rx, qx)));
        const float dist = __fsub_rn(__fadd_rn(q2, r2), __fmul_rn(2.0f, cr));
        return ((unsigned long long)fkey(dist) << 32) | (uint32_t)r;
    };

    // ---- warmup: bitonic sort of the first 64 candidates (ascending) ----
    unsigned long long v = distkey(0);
#pragma unroll
    for (int k = 2; k <= 64; k <<= 1) {
#pragma unroll
        for (int j = k >> 1; j > 0; j >>= 1) {
            const unsigned long long o = __shfl_xor(v, j, 64);
            const bool keepMin = (((lane & k) == 0) == ((lane & j) == 0));
            const bool omin = o < v;
            v = (keepMin == omin) ? o : v;  // keepMin ? min(v,o) : max(v,o)
        }
    }
    unsigned long long lkey = (lane < KNN) ? v : ~0ull;
    unsigned long long tau = __shfl(lkey, 15, 64);  // exact running 16th-best

    // ---- main scan ----
    const int n_iter = (n_prev + 63) >> 6;  // wave-uniform trip count
    for (int t = 1; t < n_iter; ++t) {
        const unsigned long long key = distkey(t);
        unsigned long long mask = __ballot(key < tau);  // strict <: equal key impossible
        while (mask) {  // mask is wave-uniform
            const int b = (int)__builtin_ctzll(mask);
            mask &= mask - 1;
            const unsigned long long bk = __shfl(key, b, 64);
            if (bk < tau) {  // re-check: tau may have tightened this iteration
                // insert bk into the distributed sorted list, drop old lane-15
                const unsigned long long sh = __shfl_up(lkey, 1, 64);
                unsigned long long nk;
                if (lkey < bk) nk = lkey;                       // stays
                else nk = (lane == 0 || sh < bk) ? bk : sh;     // gets bk or shifts
                if (lane < KNN) lkey = nk;                      // lanes >=16 stay ~0
                tau = __shfl(lkey, 15, 64);
            }
        }
    }

    if (lane < KNN)
        knn_idx[q * KNN + lane] = (int)(lkey & 0xffffffffu);
}

// One wave per QUERY: load the shared cur row once, issue all 16 independent
// gathered prev-row float4 loads, then stream the 32 stores NONTEMPORALLY so
// the 134 MB write stream doesn't evict the 8 MB gather table from L2/LLC.
__global__ __launch_bounds__(256) void combine_kernel(
    const float* __restrict__ feat_prev, const float* __restrict__ feat_cur,
    const int* __restrict__ knn_idx, float* __restrict__ out,
    int n_cur, int c4)
{
    const int q = blockIdx.x * 4 + (threadIdx.x >> 6);
    const int lane = threadIdx.x & 63;
    if (q >= n_cur) return;

    int nb[KNN];
#pragma unroll
    for (int j = 0; j < KNN; ++j)
        nb[j] = knn_idx[q * KNN + j];

    const vfloat4* pbase = (const vfloat4*)feat_prev;
    const vfloat4* crow  = (const vfloat4*)feat_cur + (size_t)q * c4;
    const int c8 = 2 * c4;  // output row length in vfloat4

    for (int i = lane; i < c4; i += 64) {
        const vfloat4 c = crow[i];
        vfloat4 p[KNN];
#pragma unroll
        for (int j = 0; j < KNN; ++j)
            p[j] = pbase[(size_t)nb[j] * c4 + i];

#pragma unroll
        for (int j = 0; j < KNN; ++j) {
            vfloat4* orow = (vfloat4*)out + (size_t)(q * KNN + j) * c8;
            __builtin_nontemporal_store(p[j] - c, orow + i);
            __builtin_nontemporal_store(c, orow + c4 + i);
        }
    }
}

extern "C" void kernel_launch(void* const* d_in, const int* in_sizes, int n_in,
                              void* d_out, int out_size, void* d_ws, size_t ws_size,
                              hipStream_t stream) {
    const float* xyz_prev  = (const float*)d_in[0];
    const float* xyz_cur   = (const float*)d_in[1];
    const float* feat_prev = (const float*)d_in[2];
    const float* feat_cur  = (const float*)d_in[3];
    float* out = (float*)d_out;

    const int n_prev = in_sizes[0] / 3;
    const int n_cur  = in_sizes[1] / 3;
    const int C      = in_sizes[2] / n_prev;   // 256

    int* knn = (int*)d_ws;                     // n_cur*KNN*4 = 256 KB scratch

    const int knn_blocks = (n_cur + 3) / 4;    // 4 waves (queries) per block
    knn_kernel<<<knn_blocks, 256, 0, stream>>>(xyz_prev, xyz_cur, knn, n_prev, n_cur);

    const int cmb_blocks = (n_cur + 3) / 4;    // 4 waves (queries) per block
    combine_kernel<<<cmb_blocks, 256, 0, stream>>>(feat_prev, feat_cur, knn, out,
                                                   n_cur, C / 4);
}